// Round 1
// baseline (2220.163 us; speedup 1.0000x reference)
//
#include <hip/hip_runtime.h>

typedef unsigned short u16;
typedef unsigned int u32;
typedef __bf16 bf16x8 __attribute__((ext_vector_type(8)));
typedef u16 u16x8 __attribute__((ext_vector_type(8)));
typedef float floatx4 __attribute__((ext_vector_type(4)));

#define B_ 8
#define S_ 1024
#define D_ 1024
#define H_ 16
#define NREL 65  // 2*MAXREL+1

__device__ __forceinline__ float b2f(u16 u) { return __uint_as_float(((u32)u) << 16); }
__device__ __forceinline__ u16 f2b(float f) {
    u32 x = __float_as_uint(f);
    x += 0x7fffu + ((x >> 16) & 1u);  // RNE
    return (u16)(x >> 16);
}

// ---------------- 1024x1024 transpose: f32 in -> bf16 out (W -> W^T) ----------------
__global__ __launch_bounds__(256) void transpose_w(const float* __restrict__ in,
                                                   u16* __restrict__ out) {
    __shared__ u16 tile[32][33];
    int c0 = blockIdx.x * 32, r0 = blockIdx.y * 32;
    int tx = threadIdx.x & 31, ty = threadIdx.x >> 5;
#pragma unroll
    for (int i = 0; i < 32; i += 8)
        tile[ty + i][tx] = f2b(in[(size_t)(r0 + ty + i) * 1024 + c0 + tx]);
    __syncthreads();
#pragma unroll
    for (int i = 0; i < 32; i += 8)
        out[(size_t)(c0 + ty + i) * 1024 + r0 + tx] = tile[tx][ty + i];
}

// ---------------- per-(b,h) V transpose: [bh][s][64] bf16 -> [bh][d][1024] bf16 ----------------
__global__ __launch_bounds__(256) void transpose_v(const u16* __restrict__ in,
                                                   u16* __restrict__ out) {
    __shared__ u16 tile[32][33];
    int bh = blockIdx.z;
    int s0 = blockIdx.x * 32, d0 = blockIdx.y * 32;
    int tx = threadIdx.x & 31, ty = threadIdx.x >> 5;
    const u16* ib = in + (size_t)bh * S_ * 64;
    u16* ob = out + (size_t)bh * S_ * 64;
#pragma unroll
    for (int i = 0; i < 32; i += 8)
        tile[ty + i][tx] = ib[(size_t)(s0 + ty + i) * 64 + d0 + tx];
    __syncthreads();
#pragma unroll
    for (int i = 0; i < 32; i += 8)
        ob[(size_t)(d0 + ty + i) * 1024 + s0 + tx] = tile[tx][ty + i];
}

// ---------------- GEMM: C[M,1024] = A[M,K] @ WT[1024,K]^T + bias ----------------
__global__ __launch_bounds__(256, 2) void gemm_bt(
    const void* __restrict__ Av, const u16* __restrict__ WT, const float* __restrict__ bias,
    float* __restrict__ outf, u16* __restrict__ outb, int M, int K, int mode, int a_bf16,
    float scale) {
    __shared__ __align__(16) u16 As[128 * 64];
    __shared__ __align__(16) u16 Bs[128 * 64];
    int tid = threadIdx.x;
    int wave = tid >> 6, lane = tid & 63;
    int wm = (wave >> 1) * 64, wn = (wave & 1) * 64;
    int m0 = blockIdx.y * 128, n0 = blockIdx.x * 128;
    floatx4 acc[4][4] = {};
    for (int kt = 0; kt < K; kt += 64) {
        if (a_bf16) {
            const u16* A = (const u16*)Av;
#pragma unroll
            for (int i = 0; i < 4; i++) {
                int L = tid + 256 * i;
                int row = L >> 3, seg = (L & 7) * 8;
                *(uint4*)(As + row * 64 + seg) = *(const uint4*)(A + (size_t)(m0 + row) * K + kt + seg);
            }
        } else {
            const float* A = (const float*)Av;
#pragma unroll
            for (int i = 0; i < 8; i++) {
                int L = tid + 256 * i;
                int row = L >> 4, seg = (L & 15) * 4;
                float4 a = *(const float4*)(A + (size_t)(m0 + row) * K + kt + seg);
                ushort4 b;
                b.x = f2b(a.x); b.y = f2b(a.y); b.z = f2b(a.z); b.w = f2b(a.w);
                *(ushort4*)(As + row * 64 + seg) = b;
            }
        }
#pragma unroll
        for (int i = 0; i < 4; i++) {
            int L = tid + 256 * i;
            int row = L >> 3, seg = (L & 7) * 8;
            *(uint4*)(Bs + row * 64 + seg) = *(const uint4*)(WT + (size_t)(n0 + row) * K + kt + seg);
        }
        __syncthreads();
        int kb = (lane >> 4) * 8;
#pragma unroll
        for (int half = 0; half < 2; half++) {
            bf16x8 af[4], bfv[4];
#pragma unroll
            for (int mi = 0; mi < 4; mi++)
                af[mi] = *(const bf16x8*)(As + (wm + mi * 16 + (lane & 15)) * 64 + half * 32 + kb);
#pragma unroll
            for (int ni = 0; ni < 4; ni++)
                bfv[ni] = *(const bf16x8*)(Bs + (wn + ni * 16 + (lane & 15)) * 64 + half * 32 + kb);
#pragma unroll
            for (int mi = 0; mi < 4; mi++)
#pragma unroll
                for (int ni = 0; ni < 4; ni++)
                    acc[mi][ni] = __builtin_amdgcn_mfma_f32_16x16x32_bf16(af[mi], bfv[ni], acc[mi][ni], 0, 0, 0);
        }
        __syncthreads();
    }
    int lr = (lane >> 4) * 4, lc = lane & 15;
#pragma unroll
    for (int mi = 0; mi < 4; mi++) {
#pragma unroll
        for (int ni = 0; ni < 4; ni++) {
            int col = n0 + wn + ni * 16 + lc;
            float bv = bias[col];
#pragma unroll
            for (int r = 0; r < 4; r++) {
                int row = m0 + wm + mi * 16 + lr + r;
                float v = (acc[mi][ni][r] + bv) * scale;
                if (mode == 0) {
                    outf[(size_t)row * 1024 + col] = v;
                } else {
                    int b = row >> 10, s = row & 1023;
                    int hh = col >> 6, d = col & 63;
                    outb[(((size_t)(b * H_ + hh)) * S_ + s) * 64 + d] = f2b(v);
                }
            }
        }
    }
}

// ---------------- fused attention (MFMA) ----------------
// one block = (b, h, 16 q-rows); 256 threads = 4 waves.
// Wave w: Phase A col-stripe [w*256, w*256+256); Phase C d-stripe [w*16, w*16+16).
__global__ __launch_bounds__(256, 2) void attn_fused(
    const u16* __restrict__ qw, const u16* __restrict__ kw, const u16* __restrict__ vt,
    const int* __restrict__ mask, const float* __restrict__ adj,
    const float* __restrict__ relk, const float* __restrict__ relv,
    float* __restrict__ attn_out, u16* __restrict__ ctx) {
    __shared__ __align__(16) u16 s_attn[16 * 1024];  // bf16 attn, XOR-swizzled (byte ^= (row&7)<<4)
    __shared__ float s_qrel[16 * NREL];              // q . rel_k[v]
    __shared__ float s_arel[16 * NREL];              // bucketed attn sums
    __shared__ float s_redm[4 * 16];                 // per-wave row maxes
    __shared__ float s_reds[4 * 16 * 2];             // per-wave row psum/pisum

    const int tid = threadIdx.x;
    const int w = tid >> 6;
    const int lane = tid & 63;
    const int g = lane >> 4;   // 0..3
    const int li = lane & 15;  // 0..15
    const int q0 = blockIdx.x * 16;
    const int h = blockIdx.y, b = blockIdx.z;
    const size_t bh = (size_t)b * H_ + h;
    const u16* qb = qw + bh * S_ * 64;
    const u16* kb = kw + bh * S_ * 64;

    // ---- Q A-frags: row m = q0+li, k = kf*32 + g*8 + j (gemm_bt A convention) ----
    bf16x8 aq[2];
#pragma unroll
    for (int kf = 0; kf < 2; kf++)
        aq[kf] = *(const bf16x8*)(qb + (size_t)(q0 + li) * 64 + kf * 32 + g * 8);

    // ---- qrel[q][v] = q . rel_k[v] via MFMA (B-frag = rel_k rows, f32->bf16 inline) ----
    for (int ni = w; ni < 5; ni += 4) {
        floatx4 qacc = {};
        int v = ni * 16 + li;
        int vc = v > 64 ? 64 : v;  // clamp row for the padded tail frag
#pragma unroll
        for (int kf = 0; kf < 2; kf++) {
            const float* rp = relk + vc * 64 + kf * 32 + g * 8;
            float4 f0 = *(const float4*)(rp);
            float4 f1 = *(const float4*)(rp + 4);
            u16x8 t;
            t[0] = f2b(f0.x); t[1] = f2b(f0.y); t[2] = f2b(f0.z); t[3] = f2b(f0.w);
            t[4] = f2b(f1.x); t[5] = f2b(f1.y); t[6] = f2b(f1.z); t[7] = f2b(f1.w);
            qacc = __builtin_amdgcn_mfma_f32_16x16x32_bf16(aq[kf], *(bf16x8*)&t, qacc, 0, 0, 0);
        }
        if (v <= 64) {
#pragma unroll
            for (int r = 0; r < 4; r++) s_qrel[(g * 4 + r) * NREL + v] = qacc[r];
        }
    }
    __syncthreads();

    // ---- Phase A: scores = Q @ K^T via MFMA (B-frag = K rows, direct from global) ----
    floatx4 acc[16] = {};
#pragma unroll
    for (int kf = 0; kf < 2; kf++) {
#pragma unroll
        for (int ni = 0; ni < 16; ni++) {
            int kcol = w * 256 + ni * 16 + li;
            bf16x8 bk = *(const bf16x8*)(kb + (size_t)kcol * 64 + kf * 32 + g * 8);
            acc[ni] = __builtin_amdgcn_mfma_f32_16x16x32_bf16(aq[kf], bk, acc[ni], 0, 0, 0);
        }
    }

    // ---- epilogue: + qrel, mask, adj-disconnect ----
    const int* mbase = mask + (size_t)b * S_ * S_;
    const float* abase = adj + bh * S_ * S_;
#pragma unroll
    for (int ni = 0; ni < 16; ni++) {
        int kcol = w * 256 + ni * 16 + li;
#pragma unroll
        for (int r = 0; r < 4; r++) {
            int qpos = q0 + g * 4 + r;
            int dd = kcol - qpos;
            dd = max(-32, min(32, dd));
            float sc = acc[ni][r] + s_qrel[(g * 4 + r) * NREL + dd + 32];
            int mk = mbase[(size_t)qpos * S_ + kcol];
            float aj = abase[(size_t)qpos * S_ + kcol];
            if (mk != 0 || aj == 0.f) sc = -1e18f;
            acc[ni][r] = sc;
        }
    }

    // ---- row max: in-lane over ni, shfl over 16-lane col group, LDS over waves ----
    float mr[4];
#pragma unroll
    for (int r = 0; r < 4; r++) {
        float m = acc[0][r];
#pragma unroll
        for (int ni = 1; ni < 16; ni++) m = fmaxf(m, acc[ni][r]);
#pragma unroll
        for (int o = 8; o > 0; o >>= 1) m = fmaxf(m, __shfl_xor(m, o, 16));
        mr[r] = m;
    }
    if (li == 0) {
#pragma unroll
        for (int r = 0; r < 4; r++) s_redm[w * 16 + g * 4 + r] = mr[r];
    }
    __syncthreads();
#pragma unroll
    for (int r = 0; r < 4; r++) {
        float m = s_redm[g * 4 + r];
#pragma unroll
        for (int ww = 1; ww < 4; ww++) m = fmaxf(m, s_redm[ww * 16 + g * 4 + r]);
        mr[r] = m;
    }

    // ---- exp + adj renorm weights; row sums ----
    float psum[4] = {0.f, 0.f, 0.f, 0.f}, pisum[4] = {0.f, 0.f, 0.f, 0.f};
#pragma unroll
    for (int ni = 0; ni < 16; ni++) {
        int kcol = w * 256 + ni * 16 + li;
#pragma unroll
        for (int r = 0; r < 4; r++) {
            int qpos = q0 + g * 4 + r;
            float aj = abase[(size_t)qpos * S_ + kcol];
            float p = __expf(acc[ni][r] - mr[r]);
            float inv = (aj != 0.f) ? (1.f / aj) : 1e-18f;
            float pi = p * inv;
            acc[ni][r] = pi;
            psum[r] += p;
            pisum[r] += pi;
        }
    }
#pragma unroll
    for (int r = 0; r < 4; r++)
#pragma unroll
        for (int o = 8; o > 0; o >>= 1) {
            psum[r] += __shfl_xor(psum[r], o, 16);
            pisum[r] += __shfl_xor(pisum[r], o, 16);
        }
    if (li == 0) {
#pragma unroll
        for (int r = 0; r < 4; r++) {
            s_reds[(w * 16 + g * 4 + r) * 2 + 0] = psum[r];
            s_reds[(w * 16 + g * 4 + r) * 2 + 1] = pisum[r];
        }
    }
    __syncthreads();
    float rden[4];
#pragma unroll
    for (int r = 0; r < 4; r++) {
        float ps = 0.f, pis = 0.f;
#pragma unroll
        for (int ww = 0; ww < 4; ww++) {
            ps += s_reds[(ww * 16 + g * 4 + r) * 2 + 0];
            pis += s_reds[(ww * 16 + g * 4 + r) * 2 + 1];
        }
        rden[r] = 1.f / fmaxf(pis, 1e-12f * ps);
    }

    // ---- finalize attn: f32 -> global, bf16 -> swizzled LDS ----
    float* ob = attn_out + bh * (size_t)S_ * S_;
#pragma unroll
    for (int ni = 0; ni < 16; ni++) {
        int kcol = w * 256 + ni * 16 + li;
#pragma unroll
        for (int r = 0; r < 4; r++) {
            int row = g * 4 + r;
            float at = acc[ni][r] * rden[r];
            ob[(size_t)(q0 + row) * S_ + kcol] = at;
            int byteoff = (row * 2048 + kcol * 2) ^ ((row & 7) << 4);
            *(u16*)((char*)s_attn + byteoff) = f2b(at);
        }
    }
    __syncthreads();

    // ---- bucket attn into 65 rel-distance bins (reads bf16 attn from LDS) ----
    {
        const int row = tid >> 4, sub = tid & 15;
        const int qpos = q0 + row;
        auto rd = [&](int k) -> float {
            int byteoff = (row * 2048 + k * 2) ^ ((row & 7) << 4);
            return b2f(*(const u16*)((const char*)s_attn + byteoff));
        };
        float s0v = 0.f;
        for (int k = sub; k <= qpos - 32; k += 16) s0v += rd(k);
#pragma unroll
        for (int o = 8; o > 0; o >>= 1) s0v += __shfl_xor(s0v, o, 16);
        if (sub == 0) s_arel[row * NREL + 0] = s0v;
        float s1v = 0.f;
        for (int k = qpos + 32 + sub; k < S_; k += 16) s1v += rd(k);
#pragma unroll
        for (int o = 8; o > 0; o >>= 1) s1v += __shfl_xor(s1v, o, 16);
        if (sub == 0) s_arel[row * NREL + 64] = s1v;
        for (int i = sub; i < 63; i += 16) {
            int v = 1 + i;
            int k = qpos + v - 32;
            s_arel[row * NREL + v] = (k >= 0 && k < S_) ? rd(k) : 0.f;
        }
    }

    // ---- Phase C: ctx = attn @ V via MFMA (A from swizzled LDS, B = V^T rows from global) ----
    floatx4 pv = {};
    const int d = w * 16 + li;
    const u16* vrow = vt + (bh * 64 + d) * (size_t)S_;
#pragma unroll 8
    for (int kt = 0; kt < S_; kt += 32) {
        int byteoff = (li * 2048 + (kt + g * 8) * 2) ^ ((li & 7) << 4);
        bf16x8 pa = *(const bf16x8*)((const char*)s_attn + byteoff);
        bf16x8 vb8 = *(const bf16x8*)(vrow + kt + g * 8);
        pv = __builtin_amdgcn_mfma_f32_16x16x32_bf16(pa, vb8, pv, 0, 0, 0);
    }
    __syncthreads();  // s_arel ready across waves

    // ---- + bucketed rel_v term; store ctx bf16 ----
#pragma unroll 1
    for (int v = 0; v < NREL; v++) {
        float rv = relv[v * 64 + d];
#pragma unroll
        for (int r = 0; r < 4; r++) pv[r] += s_arel[(g * 4 + r) * NREL + v] * rv;
    }
    u16* cb = ctx + ((size_t)b * S_ + q0) * 1024 + h * 64 + d;
#pragma unroll
    for (int r = 0; r < 4; r++) cb[(size_t)(g * 4 + r) * 1024] = f2b(pv[r]);
}

extern "C" void kernel_launch(void* const* d_in, const int* in_sizes, int n_in,
                              void* d_out, int out_size, void* d_ws, size_t ws_size,
                              hipStream_t stream) {
    const float* key   = (const float*)d_in[0];
    const float* value = (const float*)d_in[1];
    const float* query = (const float*)d_in[2];
    const int* mask    = (const int*)d_in[3];   // bool in ref -> int32 upload
    const float* adj   = (const float*)d_in[4];
    const float* Wq = (const float*)d_in[5];  const float* bq = (const float*)d_in[6];
    const float* Wk = (const float*)d_in[7];  const float* bk = (const float*)d_in[8];
    const float* Wv = (const float*)d_in[9];  const float* bv = (const float*)d_in[10];
    const float* Wo = (const float*)d_in[11]; const float* bo = (const float*)d_in[12];
    const float* relk = (const float*)d_in[13];
    const float* relv = (const float*)d_in[14];

    float* out_final = (float*)d_out;
    float* out_attn  = out_final + (size_t)B_ * S_ * D_;

    char* ws = (char*)d_ws;
    u16* wt  = (u16*)ws;                               // 2MB transposed weight (bf16)
    u16* qws = (u16*)(ws + ((size_t)2 << 20));         // [B,H,S,64] bf16, 16MB
    u16* kws = (u16*)(ws + ((size_t)18 << 20));        // 16MB
    u16* vws = (u16*)(ws + ((size_t)34 << 20));        // 16MB
    u16* vtw = (u16*)(ws + ((size_t)50 << 20));        // V^T [B,H,64,S] bf16 16MB
    u16* cws = (u16*)(ws + ((size_t)66 << 20));        // ctx [B*S, H*64] bf16 16MB

    dim3 tg(32, 32), tb(256);
    dim3 gg(8, 64), gb(256);
    dim3 vg(32, 2, 128), vb_(256);
    dim3 ag(64, 16, 8), ab(256);

    transpose_w<<<tg, tb, 0, stream>>>(Wq, wt);
    gemm_bt<<<gg, gb, 0, stream>>>(query, wt, bq, nullptr, qws, 8192, 1024, 1, 0, 0.125f);
    transpose_w<<<tg, tb, 0, stream>>>(Wk, wt);
    gemm_bt<<<gg, gb, 0, stream>>>(key, wt, bk, nullptr, kws, 8192, 1024, 1, 0, 1.0f);
    transpose_w<<<tg, tb, 0, stream>>>(Wv, wt);
    gemm_bt<<<gg, gb, 0, stream>>>(value, wt, bv, nullptr, vws, 8192, 1024, 1, 0, 1.0f);
    transpose_v<<<vg, vb_, 0, stream>>>(vws, vtw);
    attn_fused<<<ag, ab, 0, stream>>>(qws, kws, vtw, mask, adj, relk, relv, out_attn, cws);
    transpose_w<<<tg, tb, 0, stream>>>(Wo, wt);
    gemm_bt<<<gg, gb, 0, stream>>>(cws, wt, bo, out_final, nullptr, 8192, 1024, 0, 1, 1.0f);
}

// Round 2
// 2002.883 us; speedup vs baseline: 1.1085x; 1.1085x over previous
//
#include <hip/hip_runtime.h>

typedef unsigned short u16;
typedef unsigned int u32;
typedef __bf16 bf16x8 __attribute__((ext_vector_type(8)));
typedef u16 u16x8 __attribute__((ext_vector_type(8)));
typedef float floatx4 __attribute__((ext_vector_type(4)));

#define B_ 8
#define S_ 1024
#define D_ 1024
#define H_ 16
#define NREL 65  // 2*MAXREL+1

__device__ __forceinline__ float b2f(u16 u) { return __uint_as_float(((u32)u) << 16); }
__device__ __forceinline__ u16 f2b(float f) {
    u32 x = __float_as_uint(f);
    x += 0x7fffu + ((x >> 16) & 1u);  // RNE
    return (u16)(x >> 16);
}

// ---------------- fused 4x 1024x1024 transpose: f32 in -> bf16 out (W -> W^T) ----------------
__global__ __launch_bounds__(256) void transpose_w4(
    const float* __restrict__ w0, const float* __restrict__ w1,
    const float* __restrict__ w2, const float* __restrict__ w3,
    u16* __restrict__ out) {
    __shared__ u16 tile[32][33];
    int z = blockIdx.z;
    const float* in = (z == 0) ? w0 : (z == 1) ? w1 : (z == 2) ? w2 : w3;
    u16* o = out + (size_t)z * 1024 * 1024;
    int c0 = blockIdx.x * 32, r0 = blockIdx.y * 32;
    int tx = threadIdx.x & 31, ty = threadIdx.x >> 5;
#pragma unroll
    for (int i = 0; i < 32; i += 8)
        tile[ty + i][tx] = f2b(in[(size_t)(r0 + ty + i) * 1024 + c0 + tx]);
    __syncthreads();
#pragma unroll
    for (int i = 0; i < 32; i += 8)
        o[(size_t)(c0 + ty + i) * 1024 + r0 + tx] = tile[tx][ty + i];
}

// ---------------- per-(b,h) V transpose: [bh][s][64] bf16 -> [bh][d][1024] bf16 ----------------
__global__ __launch_bounds__(256) void transpose_v(const u16* __restrict__ in,
                                                   u16* __restrict__ out) {
    __shared__ u16 tile[32][33];
    int bh = blockIdx.z;
    int s0 = blockIdx.x * 32, d0 = blockIdx.y * 32;
    int tx = threadIdx.x & 31, ty = threadIdx.x >> 5;
    const u16* ib = in + (size_t)bh * S_ * 64;
    u16* ob = out + (size_t)bh * S_ * 64;
#pragma unroll
    for (int i = 0; i < 32; i += 8)
        tile[ty + i][tx] = ib[(size_t)(s0 + ty + i) * 64 + d0 + tx];
    __syncthreads();
#pragma unroll
    for (int i = 0; i < 32; i += 8)
        ob[(size_t)(d0 + ty + i) * 1024 + s0 + tx] = tile[tx][ty + i];
}

// ---------------- fused QKV GEMM: out[z] = inp[z] @ WT[z]^T + bias[z] (head-major bf16) ----------------
__global__ __launch_bounds__(256, 2) void gemm_qkv(
    const float* __restrict__ Aq, const float* __restrict__ Ak, const float* __restrict__ Avv,
    const u16* __restrict__ wt4, const float* __restrict__ bq, const float* __restrict__ bk,
    const float* __restrict__ bv, u16* __restrict__ oq, u16* __restrict__ ok,
    u16* __restrict__ ov) {
    __shared__ __align__(16) u16 As[128 * 64];
    __shared__ __align__(16) u16 Bs[128 * 64];
    int z = blockIdx.z;
    const float* A = (z == 0) ? Aq : (z == 1) ? Ak : Avv;
    const u16* WT = wt4 + (size_t)z * 1024 * 1024;
    const float* bias = (z == 0) ? bq : (z == 1) ? bk : bv;
    u16* outb = (z == 0) ? oq : (z == 1) ? ok : ov;
    float scale = (z == 0) ? 0.125f : 1.0f;
    int tid = threadIdx.x;
    int wave = tid >> 6, lane = tid & 63;
    int wm = (wave >> 1) * 64, wn = (wave & 1) * 64;
    int m0 = blockIdx.y * 128, n0 = blockIdx.x * 128;
    floatx4 acc[4][4] = {};
    for (int kt = 0; kt < 1024; kt += 64) {
#pragma unroll
        for (int i = 0; i < 8; i++) {
            int L = tid + 256 * i;
            int row = L >> 4, seg = (L & 15) * 4;
            float4 a = *(const float4*)(A + (size_t)(m0 + row) * 1024 + kt + seg);
            ushort4 bb;
            bb.x = f2b(a.x); bb.y = f2b(a.y); bb.z = f2b(a.z); bb.w = f2b(a.w);
            *(ushort4*)(As + row * 64 + seg) = bb;
        }
#pragma unroll
        for (int i = 0; i < 4; i++) {
            int L = tid + 256 * i;
            int row = L >> 3, seg = (L & 7) * 8;
            *(uint4*)(Bs + row * 64 + seg) = *(const uint4*)(WT + (size_t)(n0 + row) * 1024 + kt + seg);
        }
        __syncthreads();
        int kb = (lane >> 4) * 8;
#pragma unroll
        for (int half = 0; half < 2; half++) {
            bf16x8 af[4], bfv[4];
#pragma unroll
            for (int mi = 0; mi < 4; mi++)
                af[mi] = *(const bf16x8*)(As + (wm + mi * 16 + (lane & 15)) * 64 + half * 32 + kb);
#pragma unroll
            for (int ni = 0; ni < 4; ni++)
                bfv[ni] = *(const bf16x8*)(Bs + (wn + ni * 16 + (lane & 15)) * 64 + half * 32 + kb);
#pragma unroll
            for (int mi = 0; mi < 4; mi++)
#pragma unroll
                for (int ni = 0; ni < 4; ni++)
                    acc[mi][ni] = __builtin_amdgcn_mfma_f32_16x16x32_bf16(af[mi], bfv[ni], acc[mi][ni], 0, 0, 0);
        }
        __syncthreads();
    }
    int lr = (lane >> 4) * 4, lc = lane & 15;
#pragma unroll
    for (int mi = 0; mi < 4; mi++) {
#pragma unroll
        for (int ni = 0; ni < 4; ni++) {
            int col = n0 + wn + ni * 16 + lc;
            float bvv = bias[col];
#pragma unroll
            for (int r = 0; r < 4; r++) {
                int row = m0 + wm + mi * 16 + lr + r;
                float v = (acc[mi][ni][r] + bvv) * scale;
                int b = row >> 10, s = row & 1023;
                int hh = col >> 6, d = col & 63;
                outb[(((size_t)(b * H_ + hh)) * S_ + s) * 64 + d] = f2b(v);
            }
        }
    }
}

// ---------------- final GEMM: out_final[8192,1024] = ctx(bf16) @ WoT^T + bo (f32 out) ----------------
__global__ __launch_bounds__(256, 2) void gemm_bt(
    const u16* __restrict__ A, const u16* __restrict__ WT, const float* __restrict__ bias,
    float* __restrict__ outf) {
    __shared__ __align__(16) u16 As[128 * 64];
    __shared__ __align__(16) u16 Bs[128 * 64];
    int tid = threadIdx.x;
    int wave = tid >> 6, lane = tid & 63;
    int wm = (wave >> 1) * 64, wn = (wave & 1) * 64;
    int m0 = blockIdx.y * 128, n0 = blockIdx.x * 128;
    floatx4 acc[4][4] = {};
    for (int kt = 0; kt < 1024; kt += 64) {
#pragma unroll
        for (int i = 0; i < 4; i++) {
            int L = tid + 256 * i;
            int row = L >> 3, seg = (L & 7) * 8;
            *(uint4*)(As + row * 64 + seg) = *(const uint4*)(A + (size_t)(m0 + row) * 1024 + kt + seg);
        }
#pragma unroll
        for (int i = 0; i < 4; i++) {
            int L = tid + 256 * i;
            int row = L >> 3, seg = (L & 7) * 8;
            *(uint4*)(Bs + row * 64 + seg) = *(const uint4*)(WT + (size_t)(n0 + row) * 1024 + kt + seg);
        }
        __syncthreads();
        int kb = (lane >> 4) * 8;
#pragma unroll
        for (int half = 0; half < 2; half++) {
            bf16x8 af[4], bfv[4];
#pragma unroll
            for (int mi = 0; mi < 4; mi++)
                af[mi] = *(const bf16x8*)(As + (wm + mi * 16 + (lane & 15)) * 64 + half * 32 + kb);
#pragma unroll
            for (int ni = 0; ni < 4; ni++)
                bfv[ni] = *(const bf16x8*)(Bs + (wn + ni * 16 + (lane & 15)) * 64 + half * 32 + kb);
#pragma unroll
            for (int mi = 0; mi < 4; mi++)
#pragma unroll
                for (int ni = 0; ni < 4; ni++)
                    acc[mi][ni] = __builtin_amdgcn_mfma_f32_16x16x32_bf16(af[mi], bfv[ni], acc[mi][ni], 0, 0, 0);
        }
        __syncthreads();
    }
    int lr = (lane >> 4) * 4, lc = lane & 15;
#pragma unroll
    for (int mi = 0; mi < 4; mi++) {
#pragma unroll
        for (int ni = 0; ni < 4; ni++) {
            int col = n0 + wn + ni * 16 + lc;
            float bvv = bias[col];
#pragma unroll
            for (int r = 0; r < 4; r++) {
                int row = m0 + wm + mi * 16 + lr + r;
                outf[(size_t)row * 1024 + col] = acc[mi][ni][r] + bvv;
            }
        }
    }
}

// ---------------- fused attention (MFMA) ----------------
// one block = (b, h, 16 q-rows); 256 threads = 4 waves; 4 blocks/CU target.
// LDS: s_attn 32KB (aj stash -> attn bf16 -> rel_v f32), s_q65 (qrel -> arel).
__global__ __launch_bounds__(256, 4) void attn_fused(
    const u16* __restrict__ qw, const u16* __restrict__ kw, const u16* __restrict__ vt,
    const int* __restrict__ mask, const float* __restrict__ adj,
    const float* __restrict__ relk, const float* __restrict__ relv,
    float* __restrict__ attn_out, u16* __restrict__ ctx) {
    __shared__ __align__(16) u16 s_attn[16 * 1024];  // XOR-swizzled (byte ^= (row&7)<<4)
    __shared__ __align__(16) float s_q65[16 * NREL];  // qrel, later reused as arel
    __shared__ float s_redm[64];
    __shared__ float s_reds[128];

    const int tid = threadIdx.x;
    const int w = tid >> 6;
    const int lane = tid & 63;
    const int g = lane >> 4;   // 0..3
    const int li = lane & 15;  // 0..15
    const int q0 = blockIdx.x * 16;
    const int h = blockIdx.y, b = blockIdx.z;
    const size_t bh = (size_t)b * H_ + h;
    const u16* qb = qw + bh * S_ * 64;
    const u16* kb = kw + bh * S_ * 64;

    // ---- Q A-frags: row m = q0+li, k = kf*32 + g*8 + j ----
    bf16x8 aq[2];
#pragma unroll
    for (int kf = 0; kf < 2; kf++)
        aq[kf] = *(const bf16x8*)(qb + (size_t)(q0 + li) * 64 + kf * 32 + g * 8);

    // ---- qrel[q][v] = q . rel_k[v] via MFMA ----
    for (int ni = w; ni < 5; ni += 4) {
        floatx4 qacc = {};
        int v = ni * 16 + li;
        int vc = v > 64 ? 64 : v;
#pragma unroll
        for (int kf = 0; kf < 2; kf++) {
            const float* rp = relk + vc * 64 + kf * 32 + g * 8;
            float4 f0 = *(const float4*)(rp);
            float4 f1 = *(const float4*)(rp + 4);
            u16x8 t;
            t[0] = f2b(f0.x); t[1] = f2b(f0.y); t[2] = f2b(f0.z); t[3] = f2b(f0.w);
            t[4] = f2b(f1.x); t[5] = f2b(f1.y); t[6] = f2b(f1.z); t[7] = f2b(f1.w);
            qacc = __builtin_amdgcn_mfma_f32_16x16x32_bf16(aq[kf], *(bf16x8*)&t, qacc, 0, 0, 0);
        }
        if (v <= 64) {
#pragma unroll
            for (int r = 0; r < 4; r++) s_q65[(g * 4 + r) * NREL + v] = qacc[r];
        }
    }
    __syncthreads();

    // ---- Phase A: scores = Q @ K^T via MFMA ----
    floatx4 acc[16] = {};
#pragma unroll
    for (int kf = 0; kf < 2; kf++) {
#pragma unroll
        for (int ni = 0; ni < 16; ni++) {
            int kcol = w * 256 + ni * 16 + li;
            bf16x8 bk = *(const bf16x8*)(kb + (size_t)kcol * 64 + kf * 32 + g * 8);
            acc[ni] = __builtin_amdgcn_mfma_f32_16x16x32_bf16(aq[kf], bk, acc[ni], 0, 0, 0);
        }
    }

    // ---- epilogue: + qrel, mask, adj-disconnect; stash aj (bf16) in s_attn (thread-private slots) ----
    const int* mbase = mask + (size_t)b * S_ * S_;
    const float* abase = adj + bh * S_ * S_;
#pragma unroll
    for (int ni = 0; ni < 16; ni++) {
        int kcol = w * 256 + ni * 16 + li;
#pragma unroll
        for (int r = 0; r < 4; r++) {
            int row = g * 4 + r;
            int qpos = q0 + row;
            int dd = kcol - qpos;
            dd = max(-32, min(32, dd));
            float sc = acc[ni][r] + s_q65[row * NREL + dd + 32];
            int mk = mbase[(size_t)qpos * S_ + kcol];
            float aj = abase[(size_t)qpos * S_ + kcol];
            *(u16*)((char*)s_attn + ((row * 2048 + kcol * 2) ^ ((row & 7) << 4))) = f2b(aj);
            if (mk != 0 || aj == 0.f) sc = -1e18f;
            acc[ni][r] = sc;
        }
    }

    // ---- row max ----
    float mr[4];
#pragma unroll
    for (int r = 0; r < 4; r++) {
        float m = acc[0][r];
#pragma unroll
        for (int ni = 1; ni < 16; ni++) m = fmaxf(m, acc[ni][r]);
#pragma unroll
        for (int o = 8; o > 0; o >>= 1) m = fmaxf(m, __shfl_xor(m, o, 16));
        mr[r] = m;
    }
    if (li == 0) {
#pragma unroll
        for (int r = 0; r < 4; r++) s_redm[w * 16 + g * 4 + r] = mr[r];
    }
    __syncthreads();
#pragma unroll
    for (int r = 0; r < 4; r++) {
        float m = s_redm[g * 4 + r];
#pragma unroll
        for (int ww = 1; ww < 4; ww++) m = fmaxf(m, s_redm[ww * 16 + g * 4 + r]);
        mr[r] = m;
    }

    // ---- exp + adj renorm (aj from LDS stash) ----
    float psum[4] = {0.f, 0.f, 0.f, 0.f}, pisum[4] = {0.f, 0.f, 0.f, 0.f};
#pragma unroll
    for (int ni = 0; ni < 16; ni++) {
        int kcol = w * 256 + ni * 16 + li;
#pragma unroll
        for (int r = 0; r < 4; r++) {
            int row = g * 4 + r;
            float aj = b2f(*(const u16*)((const char*)s_attn + ((row * 2048 + kcol * 2) ^ ((row & 7) << 4))));
            float p = __expf(acc[ni][r] - mr[r]);
            float inv = (aj != 0.f) ? (1.f / aj) : 1e-18f;
            float pi = p * inv;
            acc[ni][r] = pi;
            psum[r] += p;
            pisum[r] += pi;
        }
    }
#pragma unroll
    for (int r = 0; r < 4; r++)
#pragma unroll
        for (int o = 8; o > 0; o >>= 1) {
            psum[r] += __shfl_xor(psum[r], o, 16);
            pisum[r] += __shfl_xor(pisum[r], o, 16);
        }
    if (li == 0) {
#pragma unroll
        for (int r = 0; r < 4; r++) {
            s_reds[(w * 16 + g * 4 + r) * 2 + 0] = psum[r];
            s_reds[(w * 16 + g * 4 + r) * 2 + 1] = pisum[r];
        }
    }
    __syncthreads();
    float rden[4];
#pragma unroll
    for (int r = 0; r < 4; r++) {
        float ps = 0.f, pis = 0.f;
#pragma unroll
        for (int ww = 0; ww < 4; ww++) {
            ps += s_reds[(ww * 16 + g * 4 + r) * 2 + 0];
            pis += s_reds[(ww * 16 + g * 4 + r) * 2 + 1];
        }
        rden[r] = 1.f / fmaxf(pis, 1e-12f * ps);
    }

    // ---- finalize attn: f32 -> global, bf16 -> swizzled LDS ----
    float* ob = attn_out + bh * (size_t)S_ * S_;
#pragma unroll
    for (int ni = 0; ni < 16; ni++) {
        int kcol = w * 256 + ni * 16 + li;
#pragma unroll
        for (int r = 0; r < 4; r++) {
            int row = g * 4 + r;
            float at = acc[ni][r] * rden[r];
            ob[(size_t)(q0 + row) * S_ + kcol] = at;
            *(u16*)((char*)s_attn + ((row * 2048 + kcol * 2) ^ ((row & 7) << 4))) = f2b(at);
        }
    }
    __syncthreads();

    // ---- bucket attn into 65 rel-distance bins (arel aliases s_q65; qrel is dead) ----
    {
        const int row = tid >> 4, sub = tid & 15;
        const int qpos = q0 + row;
        auto rd = [&](int k) -> float {
            int byteoff = (row * 2048 + k * 2) ^ ((row & 7) << 4);
            return b2f(*(const u16*)((const char*)s_attn + byteoff));
        };
        float s0v = 0.f;
        for (int k = sub; k <= qpos - 32; k += 16) s0v += rd(k);
#pragma unroll
        for (int o = 8; o > 0; o >>= 1) s0v += __shfl_xor(s0v, o, 16);
        if (sub == 0) s_q65[row * NREL + 0] = s0v;
        float s1v = 0.f;
        for (int k = qpos + 32 + sub; k < S_; k += 16) s1v += rd(k);
#pragma unroll
        for (int o = 8; o > 0; o >>= 1) s1v += __shfl_xor(s1v, o, 16);
        if (sub == 0) s_q65[row * NREL + 64] = s1v;
        for (int i = sub; i < 63; i += 16) {
            int v = 1 + i;
            int k = qpos + v - 32;
            s_q65[row * NREL + v] = (k >= 0 && k < S_) ? rd(k) : 0.f;
        }
    }

    // ---- Phase C: ctx = attn @ V via MFMA ----
    floatx4 pv = {};
    const int d = w * 16 + li;
    const u16* vrow = vt + (bh * 64 + d) * (size_t)S_;
#pragma unroll 8
    for (int kt = 0; kt < S_; kt += 32) {
        int byteoff = (li * 2048 + (kt + g * 8) * 2) ^ ((li & 7) << 4);
        bf16x8 pa = *(const bf16x8*)((const char*)s_attn + byteoff);
        bf16x8 vb8 = *(const bf16x8*)(vrow + kt + g * 8);
        pv = __builtin_amdgcn_mfma_f32_16x16x32_bf16(pa, vb8, pv, 0, 0, 0);
    }
    __syncthreads();  // Phase C done everywhere; s_attn free, arel ready

    // ---- stage rel_v into LDS (reuse s_attn space), then accumulate ----
    float* s_rv = (float*)s_attn;
    {
        float4* dst = (float4*)s_rv;
        const float4* src = (const float4*)relv;
        for (int i = tid; i < NREL * 16; i += 256) dst[i] = src[i];  // 65*64 f32
    }
    __syncthreads();
#pragma unroll 4
    for (int v = 0; v < NREL; v++) {
        float rv = s_rv[v * 64 + d];
#pragma unroll
        for (int r = 0; r < 4; r++) pv[r] += s_q65[(g * 4 + r) * NREL + v] * rv;
    }
    u16* cb = ctx + ((size_t)b * S_ + q0) * 1024 + h * 64 + d;
#pragma unroll
    for (int r = 0; r < 4; r++) cb[(size_t)(g * 4 + r) * 1024] = f2b(pv[r]);
}

extern "C" void kernel_launch(void* const* d_in, const int* in_sizes, int n_in,
                              void* d_out, int out_size, void* d_ws, size_t ws_size,
                              hipStream_t stream) {
    const float* key   = (const float*)d_in[0];
    const float* value = (const float*)d_in[1];
    const float* query = (const float*)d_in[2];
    const int* mask    = (const int*)d_in[3];   // bool in ref -> int32 upload
    const float* adj   = (const float*)d_in[4];
    const float* Wq = (const float*)d_in[5];  const float* bq = (const float*)d_in[6];
    const float* Wk = (const float*)d_in[7];  const float* bk = (const float*)d_in[8];
    const float* Wv = (const float*)d_in[9];  const float* bv = (const float*)d_in[10];
    const float* Wo = (const float*)d_in[11]; const float* bo = (const float*)d_in[12];
    const float* relk = (const float*)d_in[13];
    const float* relv = (const float*)d_in[14];

    float* out_final = (float*)d_out;
    float* out_attn  = out_final + (size_t)B_ * S_ * D_;

    char* ws = (char*)d_ws;
    u16* wt4 = (u16*)ws;                               // 4 x 2MB transposed weights (Q,K,V,O)
    u16* qws = (u16*)(ws + ((size_t)8 << 20));         // [B,H,S,64] bf16, 16MB
    u16* kws = (u16*)(ws + ((size_t)24 << 20));        // 16MB
    u16* vtw = (u16*)(ws + ((size_t)40 << 20));        // V^T [B,H,64,S] bf16, 16MB
    u16* cws = (u16*)(ws + ((size_t)56 << 20));        // V (head-major) first, then ctx; 16MB
    u16* vws = cws;                                    // alias: V dead after transpose_v

    dim3 tb(256);
    dim3 t4g(32, 32, 4);
    dim3 qkvg(8, 64, 3);
    dim3 vg(32, 2, 128);
    dim3 ag(64, 16, 8);
    dim3 gg(8, 64);

    transpose_w4<<<t4g, tb, 0, stream>>>(Wq, Wk, Wv, Wo, wt4);
    gemm_qkv<<<qkvg, tb, 0, stream>>>(query, key, value, wt4, bq, bk, bv, qws, kws, vws);
    transpose_v<<<vg, tb, 0, stream>>>(vws, vtw);
    attn_fused<<<ag, tb, 0, stream>>>(qws, kws, vtw, mask, adj, relk, relv, out_attn, cws);
    gemm_bt<<<gg, tb, 0, stream>>>(cws, wt4 + (size_t)3 * 1024 * 1024, bo, out_final);
}